// Round 1
// baseline (1622.555 us; speedup 1.0000x reference)
//
#include <hip/hip_runtime.h>
#include <cstddef>

static constexpr int TPB = 256;

// ---------------------------------------------------------------- utility
__global__ void k_fill(float* __restrict__ p, float v, int n) {
    int stride = gridDim.x * blockDim.x;
    for (int i = blockIdx.x * blockDim.x + threadIdx.x; i < n; i += stride)
        p[i] = v;
}

// deg[d] += 1 per edge (deg pre-filled with 1.0 for the self-loop)
__global__ void k_deg(const int* __restrict__ dst, float* __restrict__ deg, int E) {
    int stride = gridDim.x * blockDim.x;
    for (int e = blockIdx.x * blockDim.x + threadIdx.x; e < E; e += stride)
        atomicAdd(&deg[dst[e]], 1.0f);
}

__global__ void k_rsqrt(const float* __restrict__ deg, float* __restrict__ dinv, int n) {
    int stride = gridDim.x * blockDim.x;
    for (int i = blockIdx.x * blockDim.x + threadIdx.x; i < n; i += stride)
        dinv[i] = rsqrtf(deg[i]);   // deg >= 1 always (self-loop)
}

// ---------------------------------------------------------------- h1 = x @ W1   [N,128]x[128,64]
__global__ __launch_bounds__(TPB) void k_gemm1(const float* __restrict__ x,
                                               const float* __restrict__ W1,
                                               float* __restrict__ h1, int N) {
    __shared__ float W1s[128 * 64];          // 32 KB
    {
        const float4* W1v = reinterpret_cast<const float4*>(W1);
        float4* W1sv = reinterpret_cast<float4*>(W1s);
        for (int i = threadIdx.x; i < 128 * 64 / 4; i += TPB) W1sv[i] = W1v[i];
    }
    __syncthreads();
    const int lane = threadIdx.x & 63;       // output feature
    const int wid  = threadIdx.x >> 6;       // row within group of 4
    for (int row = blockIdx.x * 4 + wid; row < N; row += gridDim.x * 4) {
        const float4* xr4 = reinterpret_cast<const float4*>(x + (size_t)row * 128);
        float acc = 0.f;
        #pragma unroll 4
        for (int k4 = 0; k4 < 32; ++k4) {
            float4 xv = xr4[k4];             // wave-uniform broadcast load
            acc = fmaf(xv.x, W1s[(k4 * 4 + 0) * 64 + lane], acc);
            acc = fmaf(xv.y, W1s[(k4 * 4 + 1) * 64 + lane], acc);
            acc = fmaf(xv.z, W1s[(k4 * 4 + 2) * 64 + lane], acc);
            acc = fmaf(xv.w, W1s[(k4 * 4 + 3) * 64 + lane], acc);
        }
        h1[(size_t)row * 64 + lane] = acc;
    }
}

// ---------------------------------------------------------------- layer-1 scatter: wave per edge
__global__ void k_agg1(const int* __restrict__ src, const int* __restrict__ dst,
                       const float* __restrict__ dinv, const float* __restrict__ h1,
                       float* __restrict__ agg1, int E) {
    int gtid = blockIdx.x * blockDim.x + threadIdx.x;
    int wid = gtid >> 6, lane = gtid & 63;
    int nwaves = (gridDim.x * blockDim.x) >> 6;
    for (int e = wid; e < E; e += nwaves) {
        int s = src[e], d = dst[e];          // wave-uniform
        float nrm = dinv[s] * dinv[d];
        float v = nrm * h1[(size_t)s * 64 + lane];
        atomicAdd(&agg1[(size_t)d * 64 + lane], v);
    }
}

// -------------------------------------- fused: +b1 +self-loop, leaky_relu, then @W2 -> h2 [N,4]
__global__ void k_final1_gemm2(const float* __restrict__ agg1, const float* __restrict__ h1,
                               const float* __restrict__ dinv, const float* __restrict__ b1,
                               const float* __restrict__ W2, float* __restrict__ h2, int N) {
    int gtid = blockIdx.x * blockDim.x + threadIdx.x;
    int wid = gtid >> 6, lane = gtid & 63;
    int nwaves = (gridDim.x * blockDim.x) >> 6;
    float4 w2 = reinterpret_cast<const float4*>(W2)[lane];   // W2[lane][0..3]
    float bl = b1[lane];
    for (int node = wid; node < N; node += nwaves) {
        float di = dinv[node];
        size_t idx = (size_t)node * 64 + lane;
        float v = agg1[idx] + di * di * h1[idx] + bl;
        v = v > 0.f ? v : 0.01f * v;                          // leaky_relu(0.01)
        float px = v * w2.x, py = v * w2.y, pz = v * w2.z, pw = v * w2.w;
        #pragma unroll
        for (int off = 32; off >= 1; off >>= 1) {
            px += __shfl_xor(px, off);
            py += __shfl_xor(py, off);
            pz += __shfl_xor(pz, off);
            pw += __shfl_xor(pw, off);
        }
        if (lane == 0)
            reinterpret_cast<float4*>(h2)[node] = make_float4(px, py, pz, pw);
    }
}

// ---------------------------------------------------------------- layer-2 scatter: thread per edge
__global__ void k_agg2(const int* __restrict__ src, const int* __restrict__ dst,
                       const float* __restrict__ dinv, const float* __restrict__ h2,
                       float* __restrict__ agg2, int E) {
    int stride = gridDim.x * blockDim.x;
    for (int e = blockIdx.x * blockDim.x + threadIdx.x; e < E; e += stride) {
        int s = src[e], d = dst[e];
        float nrm = dinv[s] * dinv[d];
        float4 v = reinterpret_cast<const float4*>(h2)[s];
        atomicAdd(&agg2[(size_t)d * 4 + 0], nrm * v.x);
        atomicAdd(&agg2[(size_t)d * 4 + 1], nrm * v.y);
        atomicAdd(&agg2[(size_t)d * 4 + 2], nrm * v.z);
        atomicAdd(&agg2[(size_t)d * 4 + 3], nrm * v.w);
    }
}

// ---------------------------------------------------------------- self-loop + b2 + softmax (in place)
__global__ void k_final2(const float* __restrict__ agg2, const float* __restrict__ h2,
                         const float* __restrict__ dinv, const float* __restrict__ b2,
                         float* __restrict__ out, int N) {
    int stride = gridDim.x * blockDim.x;
    float b0 = b2[0], b1v = b2[1], b2v = b2[2], b3 = b2[3];
    for (int i = blockIdx.x * blockDim.x + threadIdx.x; i < N; i += stride) {
        float di = dinv[i], di2 = di * di;
        float4 h = reinterpret_cast<const float4*>(h2)[i];
        float4 a = reinterpret_cast<const float4*>(agg2)[i];
        float v0 = a.x + di2 * h.x + b0;
        float v1 = a.y + di2 * h.y + b1v;
        float v2 = a.z + di2 * h.z + b2v;
        float v3 = a.w + di2 * h.w + b3;
        float m = fmaxf(fmaxf(v0, v1), fmaxf(v2, v3));
        float e0 = __expf(v0 - m), e1 = __expf(v1 - m);
        float e2 = __expf(v2 - m), e3 = __expf(v3 - m);
        float s = 1.0f / (e0 + e1 + e2 + e3);
        reinterpret_cast<float4*>(out)[i] = make_float4(e0 * s, e1 * s, e2 * s, e3 * s);
    }
}

// ----------------------------------------------------------------
extern "C" void kernel_launch(void* const* d_in, const int* in_sizes, int n_in,
                              void* d_out, int out_size, void* d_ws, size_t ws_size,
                              hipStream_t stream) {
    const float* x  = (const float*)d_in[0];
    const float* W1 = (const float*)d_in[1];
    const float* b1 = (const float*)d_in[2];
    const float* W2 = (const float*)d_in[3];
    const float* b2 = (const float*)d_in[4];
    const int*   ei = (const int*)d_in[5];

    const int N = in_sizes[0] / 128;
    const int E = in_sizes[5] / 2;
    const int* src = ei;
    const int* dst = ei + E;

    float* ws   = (float*)d_ws;
    float* deg  = ws;                         // N
    float* dinv = deg + N;                    // N
    float* h1   = dinv + N;                   // N*64
    float* agg1 = h1 + (size_t)N * 64;        // N*64
    float* h2   = agg1 + (size_t)N * 64;      // N*4
    float* agg2 = (float*)d_out;              // accumulate in d_out, finalized in place

    k_fill<<<512, TPB, 0, stream>>>(deg, 1.0f, N);
    k_fill<<<2048, TPB, 0, stream>>>(agg1, 0.0f, N * 64);
    k_fill<<<512, TPB, 0, stream>>>(agg2, 0.0f, N * 4);
    k_deg<<<2048, TPB, 0, stream>>>(dst, deg, E);
    k_rsqrt<<<512, TPB, 0, stream>>>(deg, dinv, N);
    k_gemm1<<<2048, TPB, 0, stream>>>(x, W1, h1, N);
    k_agg1<<<2048, TPB, 0, stream>>>(src, dst, dinv, h1, agg1, E);
    k_final1_gemm2<<<2048, TPB, 0, stream>>>(agg1, h1, dinv, b1, W2, h2, N);
    k_agg2<<<2048, TPB, 0, stream>>>(src, dst, dinv, h2, agg2, E);
    k_final2<<<(N + TPB - 1) / TPB, TPB, 0, stream>>>(agg2, h2, dinv, b2, (float*)d_out, N);
}

// Round 2
// 635.197 us; speedup vs baseline: 2.5544x; 2.5544x over previous
//
#include <hip/hip_runtime.h>
#include <cstddef>

static constexpr int TPB = 256;

// ---------------------------------------------------------------- utility
__global__ void k_zero_i(int* __restrict__ p, int n) {
    int stride = gridDim.x * blockDim.x;
    for (int i = blockIdx.x * blockDim.x + threadIdx.x; i < n; i += stride)
        p[i] = 0;
}

// histogram of in-degree (edges only; self-loop handled analytically)
__global__ void k_hist(const int* __restrict__ dst, int* __restrict__ cnt, int E) {
    int stride = gridDim.x * blockDim.x;
    for (int e = blockIdx.x * blockDim.x + threadIdx.x; e < E; e += stride)
        atomicAdd(&cnt[dst[e]], 1);
}

// per-block (1024-elem) sums of cnt
__global__ __launch_bounds__(TPB) void k_block_sums(const int* __restrict__ cnt,
                                                    int* __restrict__ blockSums, int N) {
    __shared__ int wsum[TPB / 64];
    int base = blockIdx.x * 1024 + threadIdx.x * 4;
    int s = 0;
    #pragma unroll
    for (int j = 0; j < 4; ++j) { int i = base + j; if (i < N) s += cnt[i]; }
    #pragma unroll
    for (int off = 32; off >= 1; off >>= 1) s += __shfl_xor(s, off);
    int lane = threadIdx.x & 63, w = threadIdx.x >> 6;
    if (lane == 0) wsum[w] = s;
    __syncthreads();
    if (threadIdx.x == 0) {
        int t = 0;
        for (int i = 0; i < TPB / 64; ++i) t += wsum[i];
        blockSums[blockIdx.x] = t;
    }
}

// sequential exclusive scan of block sums (nb <= 128: trivial)
__global__ void k_scan_sums(int* __restrict__ blockSums, int nb) {
    if (blockIdx.x == 0 && threadIdx.x == 0) {
        int run = 0;
        for (int b = 0; b < nb; ++b) { int t = blockSums[b]; blockSums[b] = run; run += t; }
    }
}

// local exclusive scan within each 1024-block + block offset -> row_start; also dinv
__global__ __launch_bounds__(TPB) void k_scan_local(const int* __restrict__ cnt,
                                                    const int* __restrict__ blockSums,
                                                    int* __restrict__ row_start,
                                                    float* __restrict__ dinv, int N) {
    __shared__ int wsum[TPB / 64];
    int base = blockIdx.x * 1024 + threadIdx.x * 4;
    int c[4];
    #pragma unroll
    for (int j = 0; j < 4; ++j) { int i = base + j; c[j] = (i < N) ? cnt[i] : 0; }
    int tsum = c[0] + c[1] + c[2] + c[3];
    int lane = threadIdx.x & 63, w = threadIdx.x >> 6;
    int v = tsum;
    #pragma unroll
    for (int off = 1; off < 64; off <<= 1) {
        int u = __shfl_up(v, off);
        if (lane >= off) v += u;
    }
    if (lane == 63) wsum[w] = v;
    __syncthreads();
    int woff = 0;
    for (int i = 0; i < w; ++i) woff += wsum[i];
    int excl = blockSums[blockIdx.x] + woff + (v - tsum);
    #pragma unroll
    for (int j = 0; j < 4; ++j) {
        int i = base + j;
        if (i < N) {
            row_start[i] = excl;
            dinv[i] = rsqrtf(1.0f + (float)c[j]);   // deg = cnt + 1 (self-loop)
            excl += c[j];
        }
    }
}

// scatter edges into CSR slots; row_start becomes row_end (cursor reuse)
__global__ void k_scatter(const int* __restrict__ src, const int* __restrict__ dst,
                          const float* __restrict__ dinv, int* __restrict__ row_cursor,
                          int2* __restrict__ csr, int E) {
    int stride = gridDim.x * blockDim.x;
    for (int e = blockIdx.x * blockDim.x + threadIdx.x; e < E; e += stride) {
        int s = src[e], d = dst[e];
        float nrm = dinv[s] * dinv[d];
        int slot = atomicAdd(&row_cursor[d], 1);
        csr[slot] = make_int2(s, __float_as_int(nrm));
    }
}

// ---------------------------------------------------------------- h1 = x @ W1   [N,128]x[128,64]
__global__ __launch_bounds__(TPB) void k_gemm1(const float* __restrict__ x,
                                               const float* __restrict__ W1,
                                               float* __restrict__ h1, int N) {
    __shared__ float W1s[128 * 64];          // 32 KB
    {
        const float4* W1v = reinterpret_cast<const float4*>(W1);
        float4* W1sv = reinterpret_cast<float4*>(W1s);
        for (int i = threadIdx.x; i < 128 * 64 / 4; i += TPB) W1sv[i] = W1v[i];
    }
    __syncthreads();
    const int lane = threadIdx.x & 63;       // output feature
    const int wid  = threadIdx.x >> 6;       // row within group of 4
    for (int row = blockIdx.x * 4 + wid; row < N; row += gridDim.x * 4) {
        const float4* xr4 = reinterpret_cast<const float4*>(x + (size_t)row * 128);
        float acc = 0.f;
        #pragma unroll 4
        for (int k4 = 0; k4 < 32; ++k4) {
            float4 xv = xr4[k4];             // wave-uniform broadcast load
            acc = fmaf(xv.x, W1s[(k4 * 4 + 0) * 64 + lane], acc);
            acc = fmaf(xv.y, W1s[(k4 * 4 + 1) * 64 + lane], acc);
            acc = fmaf(xv.z, W1s[(k4 * 4 + 2) * 64 + lane], acc);
            acc = fmaf(xv.w, W1s[(k4 * 4 + 3) * 64 + lane], acc);
        }
        h1[(size_t)row * 64 + lane] = acc;
    }
}

// ------------- layer-1 gather + bias + self-loop + leaky_relu + @W2 -> h2 [N,4], wave per node
__global__ void k_gather1(const int* __restrict__ row_end, const int* __restrict__ cnt,
                          const int2* __restrict__ csr, const float* __restrict__ dinv,
                          const float* __restrict__ h1, const float* __restrict__ b1,
                          const float* __restrict__ W2, float* __restrict__ h2, int N) {
    int gtid = blockIdx.x * blockDim.x + threadIdx.x;
    int wid = gtid >> 6, lane = gtid & 63;
    int nwaves = (gridDim.x * blockDim.x) >> 6;
    float4 w2 = reinterpret_cast<const float4*>(W2)[lane];   // W2[lane][0..3]
    float bl = b1[lane];
    for (int node = wid; node < N; node += nwaves) {
        int rc = cnt[node];
        int rs = row_end[node] - rc;
        float dn = dinv[node];
        float acc = 0.f;
        int k = 0;
        for (; k + 1 < rc; k += 2) {                 // 2-way unroll for ILP
            int2 c0 = csr[rs + k];
            int2 c1 = csr[rs + k + 1];
            float a0 = __int_as_float(c0.y) * h1[(size_t)c0.x * 64 + lane];
            float a1 = __int_as_float(c1.y) * h1[(size_t)c1.x * 64 + lane];
            acc += a0 + a1;
        }
        if (k < rc) {
            int2 c0 = csr[rs + k];
            acc += __int_as_float(c0.y) * h1[(size_t)c0.x * 64 + lane];
        }
        float v = acc + dn * dn * h1[(size_t)node * 64 + lane] + bl;
        v = v > 0.f ? v : 0.01f * v;                 // leaky_relu(0.01)
        float px = v * w2.x, py = v * w2.y, pz = v * w2.z, pw = v * w2.w;
        #pragma unroll
        for (int off = 32; off >= 1; off >>= 1) {
            px += __shfl_xor(px, off);
            py += __shfl_xor(py, off);
            pz += __shfl_xor(pz, off);
            pw += __shfl_xor(pw, off);
        }
        if (lane == 0)
            reinterpret_cast<float4*>(h2)[node] = make_float4(px, py, pz, pw);
    }
}

// ------------- layer-2 gather + self-loop + b2 + softmax -> out [N,4], thread per node
__global__ void k_gather2(const int* __restrict__ row_end, const int* __restrict__ cnt,
                          const int2* __restrict__ csr, const float* __restrict__ dinv,
                          const float* __restrict__ h2, const float* __restrict__ b2,
                          float* __restrict__ out, int N) {
    int stride = gridDim.x * blockDim.x;
    float b0 = b2[0], b1v = b2[1], b2v = b2[2], b3 = b2[3];
    for (int i = blockIdx.x * blockDim.x + threadIdx.x; i < N; i += stride) {
        int rc = cnt[i];
        int rs = row_end[i] - rc;
        float dn = dinv[i], dn2 = dn * dn;
        float4 hs = reinterpret_cast<const float4*>(h2)[i];
        float a0 = dn2 * hs.x, a1 = dn2 * hs.y, a2 = dn2 * hs.z, a3 = dn2 * hs.w;
        for (int k = 0; k < rc; ++k) {
            int2 c = csr[rs + k];
            float nrm = __int_as_float(c.y);
            float4 hv = reinterpret_cast<const float4*>(h2)[c.x];
            a0 = fmaf(nrm, hv.x, a0);
            a1 = fmaf(nrm, hv.y, a1);
            a2 = fmaf(nrm, hv.z, a2);
            a3 = fmaf(nrm, hv.w, a3);
        }
        float v0 = a0 + b0, v1 = a1 + b1v, v2 = a2 + b2v, v3 = a3 + b3;
        float m = fmaxf(fmaxf(v0, v1), fmaxf(v2, v3));
        float e0 = __expf(v0 - m), e1 = __expf(v1 - m);
        float e2 = __expf(v2 - m), e3 = __expf(v3 - m);
        float s = 1.0f / (e0 + e1 + e2 + e3);
        reinterpret_cast<float4*>(out)[i] = make_float4(e0 * s, e1 * s, e2 * s, e3 * s);
    }
}

// ----------------------------------------------------------------
extern "C" void kernel_launch(void* const* d_in, const int* in_sizes, int n_in,
                              void* d_out, int out_size, void* d_ws, size_t ws_size,
                              hipStream_t stream) {
    const float* x  = (const float*)d_in[0];
    const float* W1 = (const float*)d_in[1];
    const float* b1 = (const float*)d_in[2];
    const float* W2 = (const float*)d_in[3];
    const float* b2 = (const float*)d_in[4];
    const int*   ei = (const int*)d_in[5];

    const int N = in_sizes[0] / 128;
    const int E = in_sizes[5] / 2;
    const int* src = ei;
    const int* dst = ei + E;

    const int NB = (N + 1023) / 1024;        // scan blocks (98 for N=100000)

    char* w = (char*)d_ws;
    int*   cnt       = (int*)w;              w += (size_t)N * 4;
    int*   row_start = (int*)w;              w += (size_t)N * 4;
    int*   blockSums = (int*)w;              w += 128 * 4;
    float* dinv      = (float*)w;            w += (size_t)N * 4;
    float* h1        = (float*)w;            w += (size_t)N * 64 * 4;
    float* h2        = (float*)w;            w += (size_t)N * 4 * 4;
    int2*  csr       = (int2*)w;             // E * 8 bytes

    k_zero_i<<<256, TPB, 0, stream>>>(cnt, N);
    k_hist<<<2048, TPB, 0, stream>>>(dst, cnt, E);
    k_block_sums<<<NB, TPB, 0, stream>>>(cnt, blockSums, N);
    k_scan_sums<<<1, 64, 0, stream>>>(blockSums, NB);
    k_scan_local<<<NB, TPB, 0, stream>>>(cnt, blockSums, row_start, dinv, N);
    k_scatter<<<2048, TPB, 0, stream>>>(src, dst, dinv, row_start, csr, E);  // row_start -> row_end
    k_gemm1<<<2048, TPB, 0, stream>>>(x, W1, h1, N);
    k_gather1<<<2048, TPB, 0, stream>>>(row_start, cnt, csr, dinv, h1, b1, W2, h2, N);
    k_gather2<<<(N + TPB - 1) / TPB, TPB, 0, stream>>>(row_start, cnt, csr, dinv, h2, b2,
                                                       (float*)d_out, N);
}

// Round 5
// 597.352 us; speedup vs baseline: 2.7162x; 1.0634x over previous
//
#include <hip/hip_runtime.h>
#include <cstddef>

static constexpr int TPB = 256;

// ---------------------------------------------------------------- utility
__global__ void k_zero_i(int* __restrict__ p, int n) {
    int stride = gridDim.x * blockDim.x;
    for (int i = blockIdx.x * blockDim.x + threadIdx.x; i < n; i += stride)
        p[i] = 0;
}

// histogram of in-degree (edges only; self-loop handled analytically)
__global__ void k_hist(const int* __restrict__ dst, int* __restrict__ cnt, int E) {
    int stride = gridDim.x * blockDim.x;
    for (int e = blockIdx.x * blockDim.x + threadIdx.x; e < E; e += stride)
        atomicAdd(&cnt[dst[e]], 1);
}

// per-block (1024-elem) sums of PADDED counts (rows padded to 16 entries / 64B)
__global__ __launch_bounds__(TPB) void k_block_sums(const int* __restrict__ cnt,
                                                    int* __restrict__ blockSums, int N) {
    __shared__ int wsum[TPB / 64];
    int base = blockIdx.x * 1024 + threadIdx.x * 4;
    int s = 0;
    #pragma unroll
    for (int j = 0; j < 4; ++j) {
        int i = base + j;
        if (i < N) s += (cnt[i] + 15) & ~15;
    }
    #pragma unroll
    for (int off = 32; off >= 1; off >>= 1) s += __shfl_xor(s, off);
    int lane = threadIdx.x & 63, w = threadIdx.x >> 6;
    if (lane == 0) wsum[w] = s;
    __syncthreads();
    if (threadIdx.x == 0) {
        int t = 0;
        for (int i = 0; i < TPB / 64; ++i) t += wsum[i];
        blockSums[blockIdx.x] = t;
    }
}

// sequential exclusive scan of block sums (nb <= 128: trivial)
__global__ void k_scan_sums(int* __restrict__ blockSums, int nb) {
    if (blockIdx.x == 0 && threadIdx.x == 0) {
        int run = 0;
        for (int b = 0; b < nb; ++b) { int t = blockSums[b]; blockSums[b] = run; run += t; }
    }
}

// local exclusive scan (padded counts) -> 64B-aligned row_start; also dinv
__global__ __launch_bounds__(TPB) void k_scan_local(const int* __restrict__ cnt,
                                                    const int* __restrict__ blockSums,
                                                    int* __restrict__ row_start,
                                                    float* __restrict__ dinv, int N) {
    __shared__ int wsum[TPB / 64];
    int base = blockIdx.x * 1024 + threadIdx.x * 4;
    int c[4], p[4];
    #pragma unroll
    for (int j = 0; j < 4; ++j) {
        int i = base + j;
        c[j] = (i < N) ? cnt[i] : 0;
        p[j] = (c[j] + 15) & ~15;
    }
    int tsum = p[0] + p[1] + p[2] + p[3];
    int lane = threadIdx.x & 63, w = threadIdx.x >> 6;
    int v = tsum;
    #pragma unroll
    for (int off = 1; off < 64; off <<= 1) {
        int u = __shfl_up(v, off);
        if (lane >= off) v += u;
    }
    if (lane == 63) wsum[w] = v;
    __syncthreads();
    int woff = 0;
    for (int i = 0; i < w; ++i) woff += wsum[i];
    int excl = blockSums[blockIdx.x] + woff + (v - tsum);
    #pragma unroll
    for (int j = 0; j < 4; ++j) {
        int i = base + j;
        if (i < N) {
            row_start[i] = excl;
            dinv[i] = rsqrtf(1.0f + (float)c[j]);   // deg = cnt + 1 (self-loop)
            excl += p[j];
        }
    }
}

// scatter src ids into CSR slots; row_start becomes row_end (cursor reuse)
__global__ void k_scatter(const int* __restrict__ src, const int* __restrict__ dst,
                          int* __restrict__ row_cursor, int* __restrict__ csr, int E) {
    int stride = gridDim.x * blockDim.x;
    for (int e = blockIdx.x * blockDim.x + threadIdx.x; e < E; e += stride) {
        int s = src[e], d = dst[e];
        int slot = atomicAdd(&row_cursor[d], 1);
        csr[slot] = s;
    }
}

// ------------------------------------ h1s = dinv * (x @ W1)   [N,128]x[128,64], row-scaled
// quarter-wave per row: lane&15 selects 4 consecutive features, lane>>4 selects row in quad
__global__ __launch_bounds__(TPB) void k_gemm1(const float* __restrict__ x,
                                               const float* __restrict__ W1,
                                               const float* __restrict__ dinv,
                                               float* __restrict__ h1s, int N) {
    __shared__ float W1s[128 * 64];          // 32 KB
    {
        const float4* W1v = reinterpret_cast<const float4*>(W1);
        float4* W1sv = reinterpret_cast<float4*>(W1s);
        for (int i = threadIdx.x; i < 128 * 64 / 4; i += TPB) W1sv[i] = W1v[i];
    }
    __syncthreads();
    const int lane = threadIdx.x & 63;
    const int wid  = threadIdx.x >> 6;       // 4 waves
    const int q    = lane >> 4;              // row within quad
    const int f4   = (lane & 15) * 4;        // feature base
    for (int rb = blockIdx.x * 16 + wid * 4; rb < N; rb += gridDim.x * 16) {
        int row = rb + q;
        const float4* xr4 = reinterpret_cast<const float4*>(x + (size_t)row * 128);
        float dn = dinv[row];
        float ax = 0.f, ay = 0.f, az = 0.f, aw = 0.f;
        #pragma unroll 8
        for (int k4 = 0; k4 < 32; ++k4) {
            float4 xv = xr4[k4];             // quarter-uniform broadcast load
            const float4* wrow = reinterpret_cast<const float4*>(&W1s[(k4 * 4) * 64 + f4]);
            float4 w0 = wrow[0];
            float4 w1 = wrow[16];            // next k: +64 floats = +16 float4
            float4 w2 = wrow[32];
            float4 w3 = wrow[48];
            ax = fmaf(xv.x, w0.x, ax); ay = fmaf(xv.x, w0.y, ay);
            az = fmaf(xv.x, w0.z, az); aw = fmaf(xv.x, w0.w, aw);
            ax = fmaf(xv.y, w1.x, ax); ay = fmaf(xv.y, w1.y, ay);
            az = fmaf(xv.y, w1.z, az); aw = fmaf(xv.y, w1.w, aw);
            ax = fmaf(xv.z, w2.x, ax); ay = fmaf(xv.z, w2.y, ay);
            az = fmaf(xv.z, w2.z, az); aw = fmaf(xv.z, w2.w, aw);
            ax = fmaf(xv.w, w3.x, ax); ay = fmaf(xv.w, w3.y, ay);
            az = fmaf(xv.w, w3.z, az); aw = fmaf(xv.w, w3.w, aw);
        }
        reinterpret_cast<float4*>(&h1s[(size_t)row * 64 + f4])[0] =
            make_float4(ax * dn, ay * dn, az * dn, aw * dn);
    }
}

// ------------- layer-1 gather + bias + leaky_relu + @W2 -> h2s [N,4], wave per node
__global__ void k_gather1(const int* __restrict__ row_end, const int* __restrict__ cnt,
                          const int* __restrict__ csr, const float* __restrict__ dinv,
                          const float* __restrict__ h1s, const float* __restrict__ b1,
                          const float* __restrict__ W2, float* __restrict__ h2s, int N) {
    int gtid = blockIdx.x * blockDim.x + threadIdx.x;
    int wid = gtid >> 6, lane = gtid & 63;
    int nwaves = (gridDim.x * blockDim.x) >> 6;
    float4 w2 = reinterpret_cast<const float4*>(W2)[lane];   // W2[lane][0..3]
    float bl = b1[lane];
    for (int node = wid; node < N; node += nwaves) {
        int rc = cnt[node];
        int rs = row_end[node] - rc;                  // 16-aligned (64B) start
        float dn = dinv[node];
        float acc = h1s[(size_t)node * 64 + lane];    // self-loop term
        const int4* c4 = reinterpret_cast<const int4*>(csr + rs);
        int g = rc >> 2;
        for (int k = 0; k < g; ++k) {
            int4 cc = c4[k];
            float a0 = h1s[(size_t)cc.x * 64 + lane];
            float a1 = h1s[(size_t)cc.y * 64 + lane];
            float a2 = h1s[(size_t)cc.z * 64 + lane];
            float a3 = h1s[(size_t)cc.w * 64 + lane];
            acc += (a0 + a1) + (a2 + a3);
        }
        for (int k = g * 4; k < rc; ++k)
            acc += h1s[(size_t)csr[rs + k] * 64 + lane];
        float v = fmaf(dn, acc, bl);
        v = v > 0.f ? v : 0.01f * v;                 // leaky_relu(0.01)
        float px = v * w2.x, py = v * w2.y, pz = v * w2.z, pw = v * w2.w;
        #pragma unroll
        for (int off = 32; off >= 1; off >>= 1) {
            px += __shfl_xor(px, off);
            py += __shfl_xor(py, off);
            pz += __shfl_xor(pz, off);
            pw += __shfl_xor(pw, off);
        }
        if (lane == 0)
            reinterpret_cast<float4*>(h2s)[node] =
                make_float4(px * dn, py * dn, pz * dn, pw * dn);   // pre-scale by dinv
    }
}

// ------------- layer-2 gather + b2 + softmax -> out [N,4], 16 lanes per node
__global__ void k_gather2(const int* __restrict__ row_end, const int* __restrict__ cnt,
                          const int* __restrict__ csr, const float* __restrict__ dinv,
                          const float* __restrict__ h2s, const float* __restrict__ b2,
                          float* __restrict__ out, int N) {
    int gtid = blockIdx.x * blockDim.x + threadIdx.x;
    int wid = gtid >> 6, lane = gtid & 63;
    int grp = lane >> 4, l = lane & 15;
    int nslots = ((gridDim.x * blockDim.x) >> 6) * 4;
    float b0 = b2[0], b1v = b2[1], b2v = b2[2], b3 = b2[3];
    for (int node = wid * 4 + grp; node < N; node += nslots) {
        int rc = cnt[node];
        int rs = row_end[node] - rc;
        float a0 = 0.f, a1 = 0.f, a2 = 0.f, a3 = 0.f;
        for (int k = l; k < rc; k += 16) {
            int s = csr[rs + k];
            float4 hv = reinterpret_cast<const float4*>(h2s)[s];
            a0 += hv.x; a1 += hv.y; a2 += hv.z; a3 += hv.w;
        }
        #pragma unroll
        for (int off = 1; off <= 8; off <<= 1) {
            a0 += __shfl_xor(a0, off);
            a1 += __shfl_xor(a1, off);
            a2 += __shfl_xor(a2, off);
            a3 += __shfl_xor(a3, off);
        }
        if (l == 0) {
            float dn = dinv[node];
            float4 hs = reinterpret_cast<const float4*>(h2s)[node];  // self-loop
            float v0 = fmaf(dn, a0 + hs.x, b0);
            float v1 = fmaf(dn, a1 + hs.y, b1v);
            float v2 = fmaf(dn, a2 + hs.z, b2v);
            float v3 = fmaf(dn, a3 + hs.w, b3);
            float m = fmaxf(fmaxf(v0, v1), fmaxf(v2, v3));
            float e0 = __expf(v0 - m), e1 = __expf(v1 - m);
            float e2 = __expf(v2 - m), e3 = __expf(v3 - m);
            float s = 1.0f / (e0 + e1 + e2 + e3);
            reinterpret_cast<float4*>(out)[node] = make_float4(e0 * s, e1 * s, e2 * s, e3 * s);
        }
    }
}

// ----------------------------------------------------------------
extern "C" void kernel_launch(void* const* d_in, const int* in_sizes, int n_in,
                              void* d_out, int out_size, void* d_ws, size_t ws_size,
                              hipStream_t stream) {
    const float* x  = (const float*)d_in[0];
    const float* W1 = (const float*)d_in[1];
    const float* b1 = (const float*)d_in[2];
    const float* W2 = (const float*)d_in[3];
    const float* b2 = (const float*)d_in[4];
    const int*   ei = (const int*)d_in[5];

    const int N = in_sizes[0] / 128;
    const int E = in_sizes[5] / 2;
    const int* src = ei;
    const int* dst = ei + E;

    const int NB = (N + 1023) / 1024;        // scan blocks (98 for N=100000)

    char* w = (char*)d_ws;
    int*   cnt       = (int*)w;              w += (size_t)N * 4;
    int*   row_start = (int*)w;              w += (size_t)N * 4;
    int*   blockSums = (int*)w;              w += 128 * 4;
    float* dinv      = (float*)w;            w += (size_t)N * 4;
    float* h1s       = (float*)w;            w += (size_t)N * 64 * 4;
    float* h2s       = (float*)w;            w += (size_t)N * 4 * 4;
    int*   csr       = (int*)w;              // (E + 15N) * 4 bytes worst case

    k_zero_i<<<256, TPB, 0, stream>>>(cnt, N);
    k_hist<<<2048, TPB, 0, stream>>>(dst, cnt, E);
    k_block_sums<<<NB, TPB, 0, stream>>>(cnt, blockSums, N);
    k_scan_sums<<<1, 64, 0, stream>>>(blockSums, NB);
    k_scan_local<<<NB, TPB, 0, stream>>>(cnt, blockSums, row_start, dinv, N);
    k_scatter<<<2048, TPB, 0, stream>>>(src, dst, row_start, csr, E);   // row_start -> row_end
    k_gemm1<<<2048, TPB, 0, stream>>>(x, W1, dinv, h1s, N);
    k_gather1<<<2048, TPB, 0, stream>>>(row_start, cnt, csr, dinv, h1s, b1, W2, h2s, N);
    k_gather2<<<2048, TPB, 0, stream>>>(row_start, cnt, csr, dinv, h2s, b2, (float*)d_out, N);
}

// Round 7
// 456.745 us; speedup vs baseline: 3.5524x; 1.3078x over previous
//
#include <hip/hip_runtime.h>
#include <cstddef>

static constexpr int TPB = 256;
// bucket = 256 consecutive dst nodes (shift 8); NBKT = ceil(N/256) <= 512
static constexpr int MAXBKT = 512;

// ---------------------------------------------------------------- utility
__global__ void k_zero_i(int* __restrict__ p, int n) {
    int stride = gridDim.x * blockDim.x;
    for (int i = blockIdx.x * blockDim.x + threadIdx.x; i < n; i += stride)
        p[i] = 0;
}

// histogram of in-degree (edges only; self-loop handled analytically)
__global__ void k_hist(const int* __restrict__ dst, int* __restrict__ cnt, int E) {
    int stride = gridDim.x * blockDim.x;
    for (int e = blockIdx.x * blockDim.x + threadIdx.x; e < E; e += stride)
        atomicAdd(&cnt[dst[e]], 1);
}

// per-block (1024-elem) sums of PADDED counts (rows padded to 16 entries / 64B)
__global__ __launch_bounds__(TPB) void k_block_sums(const int* __restrict__ cnt,
                                                    int* __restrict__ blockSums, int N) {
    __shared__ int wsum[TPB / 64];
    int base = blockIdx.x * 1024 + threadIdx.x * 4;
    int s = 0;
    #pragma unroll
    for (int j = 0; j < 4; ++j) {
        int i = base + j;
        if (i < N) s += (cnt[i] + 15) & ~15;
    }
    #pragma unroll
    for (int off = 32; off >= 1; off >>= 1) s += __shfl_xor(s, off);
    int lane = threadIdx.x & 63, w = threadIdx.x >> 6;
    if (lane == 0) wsum[w] = s;
    __syncthreads();
    if (threadIdx.x == 0) {
        int t = 0;
        for (int i = 0; i < TPB / 64; ++i) t += wsum[i];
        blockSums[blockIdx.x] = t;
    }
}

// sequential exclusive scan of block sums (nb <= 128: trivial)
__global__ void k_scan_sums(int* __restrict__ blockSums, int nb) {
    if (blockIdx.x == 0 && threadIdx.x == 0) {
        int run = 0;
        for (int b = 0; b < nb; ++b) { int t = blockSums[b]; blockSums[b] = run; run += t; }
    }
}

// local exclusive scan (padded counts) -> 64B-aligned row_start; also dinv
__global__ __launch_bounds__(TPB) void k_scan_local(const int* __restrict__ cnt,
                                                    const int* __restrict__ blockSums,
                                                    int* __restrict__ row_start,
                                                    float* __restrict__ dinv, int N) {
    __shared__ int wsum[TPB / 64];
    int base = blockIdx.x * 1024 + threadIdx.x * 4;
    int c[4], p[4];
    #pragma unroll
    for (int j = 0; j < 4; ++j) {
        int i = base + j;
        c[j] = (i < N) ? cnt[i] : 0;
        p[j] = (c[j] + 15) & ~15;
    }
    int tsum = p[0] + p[1] + p[2] + p[3];
    int lane = threadIdx.x & 63, w = threadIdx.x >> 6;
    int v = tsum;
    #pragma unroll
    for (int off = 1; off < 64; off <<= 1) {
        int u = __shfl_up(v, off);
        if (lane >= off) v += u;
    }
    if (lane == 63) wsum[w] = v;
    __syncthreads();
    int woff = 0;
    for (int i = 0; i < w; ++i) woff += wsum[i];
    int excl = blockSums[blockIdx.x] + woff + (v - tsum);
    #pragma unroll
    for (int j = 0; j < 4; ++j) {
        int i = base + j;
        if (i < N) {
            row_start[i] = excl;
            dinv[i] = rsqrtf(1.0f + (float)c[j]);   // deg = cnt + 1 (self-loop)
            excl += p[j];
        }
    }
}

// tight per-bucket edge-count scan -> bucket_lo (start in pairs array) + pair_cur (cursor)
__global__ __launch_bounds__(TPB) void k_bucket_scan(const int* __restrict__ cnt, int N,
                                                     int nbkt, int* __restrict__ bucket_lo,
                                                     int* __restrict__ pair_cur) {
    __shared__ int bsum[MAXBKT];
    int t = threadIdx.x;                       // single block
    for (int b = t; b < nbkt; b += TPB) {
        int lo = b << 8, hi = min(lo + 256, N);
        int s = 0;
        for (int i = lo; i < hi; ++i) s += cnt[i];
        bsum[b] = s;
    }
    __syncthreads();
    if (t == 0) {
        int run = 0;
        for (int b = 0; b < nbkt; ++b) { int c = bsum[b]; bsum[b] = run; run += c; }
    }
    __syncthreads();
    for (int b = t; b < nbkt; b += TPB) {
        bucket_lo[b] = bsum[b];
        pair_cur[b]  = bsum[b];
    }
}

// pass 1: partition edges into 256-node buckets; per-(block,bucket) private contiguous
// sub-ranges -> mostly full-line, single-writer HBM writes. pairs entry = (s<<8)|(d&255).
__global__ __launch_bounds__(TPB) void k_partition(const int* __restrict__ src,
                                                   const int* __restrict__ dst,
                                                   int* __restrict__ pair_cur,
                                                   int* __restrict__ pairs, int E, int nbkt) {
    __shared__ int hist[MAXBKT];
    __shared__ int base[MAXBKT];
    const int chunk = (E + gridDim.x - 1) / gridDim.x;
    const int e0 = blockIdx.x * chunk;
    const int e1 = min(e0 + chunk, E);
    for (int b = threadIdx.x; b < nbkt; b += TPB) hist[b] = 0;
    __syncthreads();
    for (int e = e0 + threadIdx.x; e < e1; e += TPB)
        atomicAdd(&hist[dst[e] >> 8], 1);
    __syncthreads();
    for (int b = threadIdx.x; b < nbkt; b += TPB) {
        int h = hist[b];
        base[b] = h ? atomicAdd(&pair_cur[b], h) : 0;
    }
    __syncthreads();
    for (int e = e0 + threadIdx.x; e < e1; e += TPB) {
        int s = src[e], d = dst[e];
        int slot = atomicAdd(&base[d >> 8], 1);
        pairs[slot] = (s << 8) | (d & 255);    // s < 2^17 -> fits
    }
}

// pass 2: one block per bucket; per-node cursor atomics are block-private & L2-hot;
// CSR region per bucket (~50KB) is single-writer -> lines fill before eviction.
__global__ void k_scatter2(const int* __restrict__ bucket_lo, const int* __restrict__ pair_cur,
                           const int* __restrict__ pairs, int* __restrict__ row_cursor,
                           int* __restrict__ csr) {
    int b = blockIdx.x;
    int lo = bucket_lo[b], hi = pair_cur[b];
    int dbase = b << 8;
    for (int k = lo + threadIdx.x; k < hi; k += blockDim.x) {
        int p = pairs[k];
        int d = dbase | (p & 255);
        int slot = atomicAdd(&row_cursor[d], 1);
        csr[slot] = p >> 8;
    }
}

// ------------------------------------ h1s = dinv * (x @ W1)   [N,128]x[128,64], row-scaled
// quarter-wave per row: lane&15 selects 4 consecutive features, lane>>4 selects row in quad
__global__ __launch_bounds__(TPB) void k_gemm1(const float* __restrict__ x,
                                               const float* __restrict__ W1,
                                               const float* __restrict__ dinv,
                                               float* __restrict__ h1s, int N) {
    __shared__ float W1s[128 * 64];          // 32 KB
    {
        const float4* W1v = reinterpret_cast<const float4*>(W1);
        float4* W1sv = reinterpret_cast<float4*>(W1s);
        for (int i = threadIdx.x; i < 128 * 64 / 4; i += TPB) W1sv[i] = W1v[i];
    }
    __syncthreads();
    const int lane = threadIdx.x & 63;
    const int wid  = threadIdx.x >> 6;       // 4 waves
    const int q    = lane >> 4;              // row within quad
    const int f4   = (lane & 15) * 4;        // feature base
    for (int rb = blockIdx.x * 16 + wid * 4; rb < N; rb += gridDim.x * 16) {
        int row = rb + q;
        const float4* xr4 = reinterpret_cast<const float4*>(x + (size_t)row * 128);
        float dn = dinv[row];
        float ax = 0.f, ay = 0.f, az = 0.f, aw = 0.f;
        #pragma unroll 8
        for (int k4 = 0; k4 < 32; ++k4) {
            float4 xv = xr4[k4];             // quarter-uniform broadcast load
            const float4* wrow = reinterpret_cast<const float4*>(&W1s[(k4 * 4) * 64 + f4]);
            float4 w0 = wrow[0];
            float4 w1 = wrow[16];            // next k: +64 floats = +16 float4
            float4 w2 = wrow[32];
            float4 w3 = wrow[48];
            ax = fmaf(xv.x, w0.x, ax); ay = fmaf(xv.x, w0.y, ay);
            az = fmaf(xv.x, w0.z, az); aw = fmaf(xv.x, w0.w, aw);
            ax = fmaf(xv.y, w1.x, ax); ay = fmaf(xv.y, w1.y, ay);
            az = fmaf(xv.y, w1.z, az); aw = fmaf(xv.y, w1.w, aw);
            ax = fmaf(xv.z, w2.x, ax); ay = fmaf(xv.z, w2.y, ay);
            az = fmaf(xv.z, w2.z, az); aw = fmaf(xv.z, w2.w, aw);
            ax = fmaf(xv.w, w3.x, ax); ay = fmaf(xv.w, w3.y, ay);
            az = fmaf(xv.w, w3.z, az); aw = fmaf(xv.w, w3.w, aw);
        }
        reinterpret_cast<float4*>(&h1s[(size_t)row * 64 + f4])[0] =
            make_float4(ax * dn, ay * dn, az * dn, aw * dn);
    }
}

// ------------- layer-1 gather + bias + leaky_relu + @W2 -> h2s [N,4], wave per node
__global__ void k_gather1(const int* __restrict__ row_end, const int* __restrict__ cnt,
                          const int* __restrict__ csr, const float* __restrict__ dinv,
                          const float* __restrict__ h1s, const float* __restrict__ b1,
                          const float* __restrict__ W2, float* __restrict__ h2s, int N) {
    int gtid = blockIdx.x * blockDim.x + threadIdx.x;
    int wid = gtid >> 6, lane = gtid & 63;
    int nwaves = (gridDim.x * blockDim.x) >> 6;
    float4 w2 = reinterpret_cast<const float4*>(W2)[lane];   // W2[lane][0..3]
    float bl = b1[lane];
    for (int node = wid; node < N; node += nwaves) {
        int rc = cnt[node];
        int rs = row_end[node] - rc;                  // 16-aligned (64B) start
        float dn = dinv[node];
        float acc = h1s[(size_t)node * 64 + lane];    // self-loop term
        const int4* c4 = reinterpret_cast<const int4*>(csr + rs);
        int g = rc >> 2;
        for (int k = 0; k < g; ++k) {
            int4 cc = c4[k];
            float a0 = h1s[(size_t)cc.x * 64 + lane];
            float a1 = h1s[(size_t)cc.y * 64 + lane];
            float a2 = h1s[(size_t)cc.z * 64 + lane];
            float a3 = h1s[(size_t)cc.w * 64 + lane];
            acc += (a0 + a1) + (a2 + a3);
        }
        for (int k = g * 4; k < rc; ++k)
            acc += h1s[(size_t)csr[rs + k] * 64 + lane];
        float v = fmaf(dn, acc, bl);
        v = v > 0.f ? v : 0.01f * v;                 // leaky_relu(0.01)
        float px = v * w2.x, py = v * w2.y, pz = v * w2.z, pw = v * w2.w;
        #pragma unroll
        for (int off = 32; off >= 1; off >>= 1) {
            px += __shfl_xor(px, off);
            py += __shfl_xor(py, off);
            pz += __shfl_xor(pz, off);
            pw += __shfl_xor(pw, off);
        }
        if (lane == 0)
            reinterpret_cast<float4*>(h2s)[node] =
                make_float4(px * dn, py * dn, pz * dn, pw * dn);   // pre-scale by dinv
    }
}

// ------------- layer-2 gather + b2 + softmax -> out [N,4], 16 lanes per node
__global__ void k_gather2(const int* __restrict__ row_end, const int* __restrict__ cnt,
                          const int* __restrict__ csr, const float* __restrict__ dinv,
                          const float* __restrict__ h2s, const float* __restrict__ b2,
                          float* __restrict__ out, int N) {
    int gtid = blockIdx.x * blockDim.x + threadIdx.x;
    int wid = gtid >> 6, lane = gtid & 63;
    int grp = lane >> 4, l = lane & 15;
    int nslots = ((gridDim.x * blockDim.x) >> 6) * 4;
    float b0 = b2[0], b1v = b2[1], b2v = b2[2], b3 = b2[3];
    for (int node = wid * 4 + grp; node < N; node += nslots) {
        int rc = cnt[node];
        int rs = row_end[node] - rc;
        float a0 = 0.f, a1 = 0.f, a2 = 0.f, a3 = 0.f;
        for (int k = l; k < rc; k += 16) {
            int s = csr[rs + k];
            float4 hv = reinterpret_cast<const float4*>(h2s)[s];
            a0 += hv.x; a1 += hv.y; a2 += hv.z; a3 += hv.w;
        }
        #pragma unroll
        for (int off = 1; off <= 8; off <<= 1) {
            a0 += __shfl_xor(a0, off);
            a1 += __shfl_xor(a1, off);
            a2 += __shfl_xor(a2, off);
            a3 += __shfl_xor(a3, off);
        }
        if (l == 0) {
            float dn = dinv[node];
            float4 hs = reinterpret_cast<const float4*>(h2s)[node];  // self-loop
            float v0 = fmaf(dn, a0 + hs.x, b0);
            float v1 = fmaf(dn, a1 + hs.y, b1v);
            float v2 = fmaf(dn, a2 + hs.z, b2v);
            float v3 = fmaf(dn, a3 + hs.w, b3);
            float m = fmaxf(fmaxf(v0, v1), fmaxf(v2, v3));
            float e0 = __expf(v0 - m), e1 = __expf(v1 - m);
            float e2 = __expf(v2 - m), e3 = __expf(v3 - m);
            float s = 1.0f / (e0 + e1 + e2 + e3);
            reinterpret_cast<float4*>(out)[node] = make_float4(e0 * s, e1 * s, e2 * s, e3 * s);
        }
    }
}

// ----------------------------------------------------------------
extern "C" void kernel_launch(void* const* d_in, const int* in_sizes, int n_in,
                              void* d_out, int out_size, void* d_ws, size_t ws_size,
                              hipStream_t stream) {
    const float* x  = (const float*)d_in[0];
    const float* W1 = (const float*)d_in[1];
    const float* b1 = (const float*)d_in[2];
    const float* W2 = (const float*)d_in[3];
    const float* b2 = (const float*)d_in[4];
    const int*   ei = (const int*)d_in[5];

    const int N = in_sizes[0] / 128;
    const int E = in_sizes[5] / 2;
    const int* src = ei;
    const int* dst = ei + E;

    const int NB   = (N + 1023) / 1024;      // scan blocks (98 for N=100000)
    const int NBKT = (N + 255) / 256;        // 391 buckets for N=100000

    char* w = (char*)d_ws;
    int*   cnt       = (int*)w;              w += (size_t)N * 4;
    int*   row_start = (int*)w;              w += (size_t)N * 4;
    int*   blockSums = (int*)w;              w += 128 * 4;
    int*   bucket_lo = (int*)w;              w += MAXBKT * 4;
    int*   pair_cur  = (int*)w;              w += MAXBKT * 4;
    float* dinv      = (float*)w;            w += (size_t)N * 4;
    float* h1s       = (float*)w;            w += (size_t)N * 64 * 4;
    float* h2s       = (float*)w;            w += (size_t)N * 4 * 4;
    int*   csr       = (int*)w;              // (E + 15N) * 4 bytes worst case
    int*   pairs     = (int*)h1s;            // alias: consumed before k_gemm1 writes h1s

    k_zero_i<<<256, TPB, 0, stream>>>(cnt, N);
    k_hist<<<2048, TPB, 0, stream>>>(dst, cnt, E);
    k_block_sums<<<NB, TPB, 0, stream>>>(cnt, blockSums, N);
    k_scan_sums<<<1, 64, 0, stream>>>(blockSums, NB);
    k_scan_local<<<NB, TPB, 0, stream>>>(cnt, blockSums, row_start, dinv, N);
    k_bucket_scan<<<1, TPB, 0, stream>>>(cnt, N, NBKT, bucket_lo, pair_cur);
    k_partition<<<256, TPB, 0, stream>>>(src, dst, pair_cur, pairs, E, NBKT);
    k_scatter2<<<NBKT, TPB, 0, stream>>>(bucket_lo, pair_cur, pairs, row_start, csr);
    k_gemm1<<<2048, TPB, 0, stream>>>(x, W1, dinv, h1s, N);   // after pairs consumed
    k_gather1<<<2048, TPB, 0, stream>>>(row_start, cnt, csr, dinv, h1s, b1, W2, h2s, N);
    k_gather2<<<2048, TPB, 0, stream>>>(row_start, cnt, csr, dinv, h2s, b2, (float*)d_out, N);
}

// Round 9
// 285.024 us; speedup vs baseline: 5.6927x; 1.6025x over previous
//
#include <hip/hip_runtime.h>
#include <cstddef>

static constexpr int TPB = 256;
// bucket = 256 consecutive dst nodes (shift 8); NBKT = ceil(N/256) <= 512
static constexpr int MAXBKT = 512;

// ---------------------------------------------------------------- utility
__global__ void k_zero_i(int* __restrict__ p, int n) {
    int stride = gridDim.x * blockDim.x;
    for (int i = blockIdx.x * blockDim.x + threadIdx.x; i < n; i += stride)
        p[i] = 0;
}

// per-block LDS bucket histogram -> few global atomics (256 blocks x NBKT buckets)
__global__ __launch_bounds__(TPB) void k_bucket_hist(const int* __restrict__ dst,
                                                     int* __restrict__ bucket_cnt,
                                                     int E, int nbkt) {
    __shared__ int hist[MAXBKT];
    for (int b = threadIdx.x; b < nbkt; b += TPB) hist[b] = 0;
    __syncthreads();
    int stride = gridDim.x * blockDim.x;
    for (int e = blockIdx.x * blockDim.x + threadIdx.x; e < E; e += stride)
        atomicAdd(&hist[dst[e] >> 8], 1);
    __syncthreads();
    for (int b = threadIdx.x; b < nbkt; b += TPB) {
        int h = hist[b];
        if (h) atomicAdd(&bucket_cnt[b], h);
    }
}

// scan bucket counts -> bucket_lo (start in pairs array) + pair_cur (cursor)
__global__ __launch_bounds__(TPB) void k_bucket_scan(const int* __restrict__ bucket_cnt,
                                                     int nbkt, int* __restrict__ bucket_lo,
                                                     int* __restrict__ pair_cur) {
    __shared__ int bsum[MAXBKT];
    int t = threadIdx.x;
    for (int b = t; b < nbkt; b += TPB) bsum[b] = bucket_cnt[b];
    __syncthreads();
    if (t == 0) {
        int run = 0;
        for (int b = 0; b < nbkt; ++b) { int c = bsum[b]; bsum[b] = run; run += c; }
    }
    __syncthreads();
    for (int b = t; b < nbkt; b += TPB) {
        bucket_lo[b] = bsum[b];
        pair_cur[b]  = bsum[b];
    }
}

// pass 1: partition edges into 256-node buckets; per-(block,bucket) private contiguous
// sub-ranges -> mostly full-line, single-writer HBM writes. pairs entry = (s<<8)|(d&255).
__global__ __launch_bounds__(TPB) void k_partition(const int* __restrict__ src,
                                                   const int* __restrict__ dst,
                                                   int* __restrict__ pair_cur,
                                                   int* __restrict__ pairs, int E, int nbkt) {
    __shared__ int hist[MAXBKT];
    __shared__ int base[MAXBKT];
    const int chunk = (E + gridDim.x - 1) / gridDim.x;
    const int e0 = blockIdx.x * chunk;
    const int e1 = min(e0 + chunk, E);
    for (int b = threadIdx.x; b < nbkt; b += TPB) hist[b] = 0;
    __syncthreads();
    for (int e = e0 + threadIdx.x; e < e1; e += TPB)
        atomicAdd(&hist[dst[e] >> 8], 1);
    __syncthreads();
    for (int b = threadIdx.x; b < nbkt; b += TPB) {
        int h = hist[b];
        base[b] = h ? atomicAdd(&pair_cur[b], h) : 0;
    }
    __syncthreads();
    for (int e = e0 + threadIdx.x; e < e1; e += TPB) {
        int s = src[e], d = dst[e];
        int slot = atomicAdd(&base[d >> 8], 1);
        pairs[slot] = (s << 8) | (d & 255);    // s < 2^17 -> fits
    }
}

// per-bucket node counts from pairs via LDS; coalesced cnt write, zero global atomics
__global__ __launch_bounds__(TPB) void k_count2(const int* __restrict__ bucket_lo,
                                                const int* __restrict__ pair_cur,
                                                const int* __restrict__ pairs,
                                                int* __restrict__ cnt, int N) {
    __shared__ int c[256];
    int b = blockIdx.x;
    c[threadIdx.x] = 0;
    __syncthreads();
    int lo = bucket_lo[b], hi = pair_cur[b];
    for (int k = lo + threadIdx.x; k < hi; k += TPB)
        atomicAdd(&c[pairs[k] & 255], 1);
    __syncthreads();
    int node = (b << 8) + threadIdx.x;
    if (node < N) cnt[node] = c[threadIdx.x];
}

// per-block (1024-elem) sums of PADDED counts (rows padded to 16 entries / 64B)
__global__ __launch_bounds__(TPB) void k_block_sums(const int* __restrict__ cnt,
                                                    int* __restrict__ blockSums, int N) {
    __shared__ int wsum[TPB / 64];
    int base = blockIdx.x * 1024 + threadIdx.x * 4;
    int s = 0;
    #pragma unroll
    for (int j = 0; j < 4; ++j) {
        int i = base + j;
        if (i < N) s += (cnt[i] + 15) & ~15;
    }
    #pragma unroll
    for (int off = 32; off >= 1; off >>= 1) s += __shfl_xor(s, off);
    int lane = threadIdx.x & 63, w = threadIdx.x >> 6;
    if (lane == 0) wsum[w] = s;
    __syncthreads();
    if (threadIdx.x == 0) {
        int t = 0;
        for (int i = 0; i < TPB / 64; ++i) t += wsum[i];
        blockSums[blockIdx.x] = t;
    }
}

// sequential exclusive scan of block sums (nb <= 128: trivial)
__global__ void k_scan_sums(int* __restrict__ blockSums, int nb) {
    if (blockIdx.x == 0 && threadIdx.x == 0) {
        int run = 0;
        for (int b = 0; b < nb; ++b) { int t = blockSums[b]; blockSums[b] = run; run += t; }
    }
}

// local exclusive scan (padded counts) -> 64B-aligned row_start; also dinv
__global__ __launch_bounds__(TPB) void k_scan_local(const int* __restrict__ cnt,
                                                    const int* __restrict__ blockSums,
                                                    int* __restrict__ row_start,
                                                    float* __restrict__ dinv, int N) {
    __shared__ int wsum[TPB / 64];
    int base = blockIdx.x * 1024 + threadIdx.x * 4;
    int c[4], p[4];
    #pragma unroll
    for (int j = 0; j < 4; ++j) {
        int i = base + j;
        c[j] = (i < N) ? cnt[i] : 0;
        p[j] = (c[j] + 15) & ~15;
    }
    int tsum = p[0] + p[1] + p[2] + p[3];
    int lane = threadIdx.x & 63, w = threadIdx.x >> 6;
    int v = tsum;
    #pragma unroll
    for (int off = 1; off < 64; off <<= 1) {
        int u = __shfl_up(v, off);
        if (lane >= off) v += u;
    }
    if (lane == 63) wsum[w] = v;
    __syncthreads();
    int woff = 0;
    for (int i = 0; i < w; ++i) woff += wsum[i];
    int excl = blockSums[blockIdx.x] + woff + (v - tsum);
    #pragma unroll
    for (int j = 0; j < 4; ++j) {
        int i = base + j;
        if (i < N) {
            row_start[i] = excl;
            dinv[i] = rsqrtf(1.0f + (float)c[j]);   // deg = cnt + 1 (self-loop)
            excl += p[j];
        }
    }
}

// pass 2: one block per bucket; LDS cursors (zero global atomics); CSR region per
// bucket (~50KB) is single-writer and L2-resident -> lines fill before eviction.
__global__ __launch_bounds__(TPB) void k_scatter2(const int* __restrict__ bucket_lo,
                                                  const int* __restrict__ pair_cur,
                                                  const int* __restrict__ pairs,
                                                  const int* __restrict__ row_start,
                                                  int* __restrict__ csr, int N) {
    __shared__ int cur[256];
    int b = blockIdx.x;
    int node = (b << 8) + threadIdx.x;
    cur[threadIdx.x] = (node < N) ? row_start[node] : 0;
    __syncthreads();
    int lo = bucket_lo[b], hi = pair_cur[b];
    for (int k = lo + threadIdx.x; k < hi; k += TPB) {
        int p = pairs[k];
        int slot = atomicAdd(&cur[p & 255], 1);
        csr[slot] = p >> 8;
    }
}

// ------------------------------------ h1s = dinv * (x @ W1)   [N,128]x[128,64], row-scaled
// quarter-wave per row: lane&15 selects 4 consecutive features, lane>>4 selects row in quad
__global__ __launch_bounds__(TPB) void k_gemm1(const float* __restrict__ x,
                                               const float* __restrict__ W1,
                                               const float* __restrict__ dinv,
                                               float* __restrict__ h1s, int N) {
    __shared__ float W1s[128 * 64];          // 32 KB
    {
        const float4* W1v = reinterpret_cast<const float4*>(W1);
        float4* W1sv = reinterpret_cast<float4*>(W1s);
        for (int i = threadIdx.x; i < 128 * 64 / 4; i += TPB) W1sv[i] = W1v[i];
    }
    __syncthreads();
    const int lane = threadIdx.x & 63;
    const int wid  = threadIdx.x >> 6;       // 4 waves
    const int q    = lane >> 4;              // row within quad
    const int f4   = (lane & 15) * 4;        // feature base
    for (int rb = blockIdx.x * 16 + wid * 4; rb < N; rb += gridDim.x * 16) {
        int row = rb + q;
        const float4* xr4 = reinterpret_cast<const float4*>(x + (size_t)row * 128);
        float dn = dinv[row];
        float ax = 0.f, ay = 0.f, az = 0.f, aw = 0.f;
        #pragma unroll 8
        for (int k4 = 0; k4 < 32; ++k4) {
            float4 xv = xr4[k4];             // quarter-uniform broadcast load
            const float4* wrow = reinterpret_cast<const float4*>(&W1s[(k4 * 4) * 64 + f4]);
            float4 w0 = wrow[0];
            float4 w1 = wrow[16];            // next k: +64 floats = +16 float4
            float4 w2 = wrow[32];
            float4 w3 = wrow[48];
            ax = fmaf(xv.x, w0.x, ax); ay = fmaf(xv.x, w0.y, ay);
            az = fmaf(xv.x, w0.z, az); aw = fmaf(xv.x, w0.w, aw);
            ax = fmaf(xv.y, w1.x, ax); ay = fmaf(xv.y, w1.y, ay);
            az = fmaf(xv.y, w1.z, az); aw = fmaf(xv.y, w1.w, aw);
            ax = fmaf(xv.z, w2.x, ax); ay = fmaf(xv.z, w2.y, ay);
            az = fmaf(xv.z, w2.z, az); aw = fmaf(xv.z, w2.w, aw);
            ax = fmaf(xv.w, w3.x, ax); ay = fmaf(xv.w, w3.y, ay);
            az = fmaf(xv.w, w3.z, az); aw = fmaf(xv.w, w3.w, aw);
        }
        reinterpret_cast<float4*>(&h1s[(size_t)row * 64 + f4])[0] =
            make_float4(ax * dn, ay * dn, az * dn, aw * dn);
    }
}

// ------------- layer-1 gather + bias + leaky_relu + @W2 -> h2s [N,4], wave per node
__global__ void k_gather1(const int* __restrict__ row_start, const int* __restrict__ cnt,
                          const int* __restrict__ csr, const float* __restrict__ dinv,
                          const float* __restrict__ h1s, const float* __restrict__ b1,
                          const float* __restrict__ W2, float* __restrict__ h2s, int N) {
    int gtid = blockIdx.x * blockDim.x + threadIdx.x;
    int wid = gtid >> 6, lane = gtid & 63;
    int nwaves = (gridDim.x * blockDim.x) >> 6;
    float4 w2 = reinterpret_cast<const float4*>(W2)[lane];   // W2[lane][0..3]
    float bl = b1[lane];
    for (int node = wid; node < N; node += nwaves) {
        int rc = cnt[node];
        int rs = row_start[node];                     // 16-aligned (64B) start
        float dn = dinv[node];
        float acc = h1s[(size_t)node * 64 + lane];    // self-loop term
        const int4* c4 = reinterpret_cast<const int4*>(csr + rs);
        int g = rc >> 2;
        for (int k = 0; k < g; ++k) {
            int4 cc = c4[k];
            float a0 = h1s[(size_t)cc.x * 64 + lane];
            float a1 = h1s[(size_t)cc.y * 64 + lane];
            float a2 = h1s[(size_t)cc.z * 64 + lane];
            float a3 = h1s[(size_t)cc.w * 64 + lane];
            acc += (a0 + a1) + (a2 + a3);
        }
        for (int k = g * 4; k < rc; ++k)
            acc += h1s[(size_t)csr[rs + k] * 64 + lane];
        float v = fmaf(dn, acc, bl);
        v = v > 0.f ? v : 0.01f * v;                 // leaky_relu(0.01)
        float px = v * w2.x, py = v * w2.y, pz = v * w2.z, pw = v * w2.w;
        #pragma unroll
        for (int off = 32; off >= 1; off >>= 1) {
            px += __shfl_xor(px, off);
            py += __shfl_xor(py, off);
            pz += __shfl_xor(pz, off);
            pw += __shfl_xor(pw, off);
        }
        if (lane == 0)
            reinterpret_cast<float4*>(h2s)[node] =
                make_float4(px * dn, py * dn, pz * dn, pw * dn);   // pre-scale by dinv
    }
}

// ------------- layer-2 gather + b2 + softmax -> out [N,4], 16 lanes per node
__global__ void k_gather2(const int* __restrict__ row_start, const int* __restrict__ cnt,
                          const int* __restrict__ csr, const float* __restrict__ dinv,
                          const float* __restrict__ h2s, const float* __restrict__ b2,
                          float* __restrict__ out, int N) {
    int gtid = blockIdx.x * blockDim.x + threadIdx.x;
    int wid = gtid >> 6, lane = gtid & 63;
    int grp = lane >> 4, l = lane & 15;
    int nslots = ((gridDim.x * blockDim.x) >> 6) * 4;
    float b0 = b2[0], b1v = b2[1], b2v = b2[2], b3 = b2[3];
    for (int node = wid * 4 + grp; node < N; node += nslots) {
        int rc = cnt[node];
        int rs = row_start[node];
        float a0 = 0.f, a1 = 0.f, a2 = 0.f, a3 = 0.f;
        for (int k = l; k < rc; k += 16) {
            int s = csr[rs + k];
            float4 hv = reinterpret_cast<const float4*>(h2s)[s];
            a0 += hv.x; a1 += hv.y; a2 += hv.z; a3 += hv.w;
        }
        #pragma unroll
        for (int off = 1; off <= 8; off <<= 1) {
            a0 += __shfl_xor(a0, off);
            a1 += __shfl_xor(a1, off);
            a2 += __shfl_xor(a2, off);
            a3 += __shfl_xor(a3, off);
        }
        if (l == 0) {
            float dn = dinv[node];
            float4 hs = reinterpret_cast<const float4*>(h2s)[node];  // self-loop
            float v0 = fmaf(dn, a0 + hs.x, b0);
            float v1 = fmaf(dn, a1 + hs.y, b1v);
            float v2 = fmaf(dn, a2 + hs.z, b2v);
            float v3 = fmaf(dn, a3 + hs.w, b3);
            float m = fmaxf(fmaxf(v0, v1), fmaxf(v2, v3));
            float e0 = __expf(v0 - m), e1 = __expf(v1 - m);
            float e2 = __expf(v2 - m), e3 = __expf(v3 - m);
            float s = 1.0f / (e0 + e1 + e2 + e3);
            reinterpret_cast<float4*>(out)[node] = make_float4(e0 * s, e1 * s, e2 * s, e3 * s);
        }
    }
}

// ----------------------------------------------------------------
extern "C" void kernel_launch(void* const* d_in, const int* in_sizes, int n_in,
                              void* d_out, int out_size, void* d_ws, size_t ws_size,
                              hipStream_t stream) {
    const float* x  = (const float*)d_in[0];
    const float* W1 = (const float*)d_in[1];
    const float* b1 = (const float*)d_in[2];
    const float* W2 = (const float*)d_in[3];
    const float* b2 = (const float*)d_in[4];
    const int*   ei = (const int*)d_in[5];

    const int N = in_sizes[0] / 128;
    const int E = in_sizes[5] / 2;
    const int* src = ei;
    const int* dst = ei + E;

    const int NB   = (N + 1023) / 1024;      // scan blocks (98 for N=100000)
    const int NBKT = (N + 255) / 256;        // 391 buckets for N=100000

    char* w = (char*)d_ws;
    int*   cnt        = (int*)w;             w += (size_t)N * 4;
    int*   row_start  = (int*)w;             w += (size_t)N * 4;
    int*   blockSums  = (int*)w;             w += 128 * 4;
    int*   bucket_cnt = (int*)w;             w += MAXBKT * 4;
    int*   bucket_lo  = (int*)w;             w += MAXBKT * 4;
    int*   pair_cur   = (int*)w;             w += MAXBKT * 4;
    float* dinv       = (float*)w;           w += (size_t)N * 4;
    float* h1s        = (float*)w;           w += (size_t)N * 64 * 4;
    float* h2s        = (float*)w;           w += (size_t)N * 4 * 4;
    int*   csr        = (int*)w;             // (E + 15N) * 4 bytes worst case
    int*   pairs      = (int*)h1s;           // alias: consumed before k_gemm1 writes h1s

    k_zero_i<<<1, TPB, 0, stream>>>(bucket_cnt, NBKT);
    k_bucket_hist<<<256, TPB, 0, stream>>>(dst, bucket_cnt, E, NBKT);
    k_bucket_scan<<<1, TPB, 0, stream>>>(bucket_cnt, NBKT, bucket_lo, pair_cur);
    k_partition<<<256, TPB, 0, stream>>>(src, dst, pair_cur, pairs, E, NBKT);
    k_count2<<<NBKT, TPB, 0, stream>>>(bucket_lo, pair_cur, pairs, cnt, N);
    k_block_sums<<<NB, TPB, 0, stream>>>(cnt, blockSums, N);
    k_scan_sums<<<1, 64, 0, stream>>>(blockSums, NB);
    k_scan_local<<<NB, TPB, 0, stream>>>(cnt, blockSums, row_start, dinv, N);
    k_scatter2<<<NBKT, TPB, 0, stream>>>(bucket_lo, pair_cur, pairs, row_start, csr, N);
    k_gemm1<<<2048, TPB, 0, stream>>>(x, W1, dinv, h1s, N);   // after pairs consumed
    k_gather1<<<2048, TPB, 0, stream>>>(row_start, cnt, csr, dinv, h1s, b1, W2, h2s, N);
    k_gather2<<<2048, TPB, 0, stream>>>(row_start, cnt, csr, dinv, h2s, b2, (float*)d_out, N);
}